// Round 1
// baseline (2877.768 us; speedup 1.0000x reference)
//
#include <hip/hip_runtime.h>
#include <hip/hip_bf16.h>

// GraphMemoryVQ: fused distance+graph-bias argmin (two-phase bf16-MFMA + f32 rescore),
// straight-through output, EMA codebook update.
//
// Sizes (fixed): N=16384, LATENT=512 (2D=1024), K=8192.

#define NR 16384
#define DH 512
#define D2 1024
#define KS 8192
#define BK 128                 // k rows per block tile
#define BN 128                 // n rows per block tile
#define KC 64                  // inner-dim chunk staged in LDS
#define KSPLIT 4
#define KRANGE (KS / KSPLIT)   // 2048
#define NKT (KRANGE / BK)      // 16 k-tiles per block

typedef __bf16 bf16x8 __attribute__((ext_vector_type(8)));
typedef float f32x4 __attribute__((ext_vector_type(4)));

// ---- workspace layout (bytes) ----
#define WS_CNORM 0                       // 8192 f32  (approx ||c||^2)
#define WS_LOSS  32768                   // f64 loss accumulator
#define WS_NTOT  32776                   // f32 n_total accumulator
#define WS_CAND  33024                   // int2 [NR][64] (score bits, idx) = 8 MB
#define WS_WIDX  (33024 + NR * 64 * 8)   // int [NR] winners
// total ~8.5 MB

// ---------------------------------------------------------------------------
// ||codebook_k||^2 (approx-phase only; rescore recomputes its own in f32)
__global__ __launch_bounds__(64) void k_cnorm(const float* __restrict__ cb,
                                              float* __restrict__ cnorm) {
  int k = blockIdx.x, lane = threadIdx.x;
  const float* row = cb + (size_t)k * D2;
  float acc = 0.f;
#pragma unroll
  for (int j = 0; j < 4; ++j) {
    f32x4 v = *(const f32x4*)(row + j * 256 + lane * 4);
    acc += v.x * v.x + v.y * v.y + v.z * v.z + v.w * v.w;
  }
#pragma unroll
  for (int off = 32; off; off >>= 1) acc += __shfl_xor(acc, off);
  if (lane == 0) cnorm[k] = acc;
}

// ---------------------------------------------------------------------------
// Phase 1: approximate scores via bf16 MFMA, per-lane top-2 candidates.
// Swapped orientation: MFMA M axis = codebook k, N axis = data row n.
//   A frag (cb/gate): row = lane&15, kin = (lane>>4)*8 + i
//   B frag (z/ctx):   col = lane&15, kin = (lane>>4)*8 + i
//   D: col(n) = lane&15, row(k) = (lane>>4)*4 + reg      [m89-verified]
__global__ __launch_bounds__(256, 2) void k_phase1(
    const float* __restrict__ zr, const float* __restrict__ zi,
    const float* __restrict__ cr, const float* __restrict__ ci,
    const int* __restrict__ prev, const float* __restrict__ cb,
    const float* __restrict__ adj, const float* __restrict__ gw,
    const float* __restrict__ gb, const float* __restrict__ cnorm,
    int2* __restrict__ cand) {
  // tiles: 0=z, 1=ctx, 2=cb, 3=gw ; each [128 rows][64 bf16], XOR-swizzled 16B slots
  __shared__ unsigned short sbuf[4 * BK * KC];  // 64 KB

  const int tid = threadIdx.x;
  const int lane = tid & 63;
  const int wid = tid >> 6;      // 4 waves
  const int wavek = wid >> 1;    // 0..1 : k half (64 rows)
  const int waven = wid & 1;     // 0..1 : n half (64 cols)
  const int r16 = lane & 15;
  const int quad = lane >> 4;
  const int n0 = blockIdx.x * BN;
  const int bk = blockIdx.y;

  int nout[4];
  const float* arow[4];
#pragma unroll
  for (int nf = 0; nf < 4; ++nf) {
    nout[nf] = n0 + waven * 64 + nf * 16 + r16;
    arow[nf] = adj + (size_t)prev[nout[nf]] * KS;
  }

  float v0[4], v1[4];
  int i0[4], i1[4];
#pragma unroll
  for (int nf = 0; nf < 4; ++nf) { v0[nf] = 3.4e38f; v1[nf] = 3.4e38f; i0[nf] = 0; i1[nf] = 0; }

  for (int kt = 0; kt < NKT; ++kt) {
    const int k0 = bk * KRANGE + kt * BK;
    f32x4 accS[4][4], accX[4][4];
#pragma unroll
    for (int a = 0; a < 4; ++a)
#pragma unroll
      for (int b = 0; b < 4; ++b) {
        accS[a][b] = (f32x4){0.f, 0.f, 0.f, 0.f};
        accX[a][b] = (f32x4){0.f, 0.f, 0.f, 0.f};
      }

    for (int c = 0; c < D2 / KC; ++c) {  // 16 chunks over the 1024 inner dim
      // ---- stage: f32 global -> bf16 LDS (16 units of 8 elems per thread) ----
#pragma unroll
      for (int u = 0; u < 16; ++u) {
        const int tile = u >> 2;                    // compile-time per u
        const int row = (u & 3) * 32 + (tid >> 3);  // 0..127
        const int kg = tid & 7;
        const int col = c * KC + kg * 8;            // 0..1023 within concat dim
        const float* src;
        if (tile == 0)
          src = (col < DH) ? zr + (size_t)(n0 + row) * DH + col
                           : zi + (size_t)(n0 + row) * DH + (col - DH);
        else if (tile == 1)
          src = (col < DH) ? cr + (size_t)(n0 + row) * DH + col
                           : ci + (size_t)(n0 + row) * DH + (col - DH);
        else if (tile == 2)
          src = cb + (size_t)(k0 + row) * D2 + col;
        else
          src = gw + (size_t)(k0 + row) * D2 + col;
        f32x4 f0 = *(const f32x4*)src;
        f32x4 f1 = *(const f32x4*)(src + 4);
        bf16x8 h;
        h[0] = (__bf16)f0.x; h[1] = (__bf16)f0.y; h[2] = (__bf16)f0.z; h[3] = (__bf16)f0.w;
        h[4] = (__bf16)f1.x; h[5] = (__bf16)f1.y; h[6] = (__bf16)f1.z; h[7] = (__bf16)f1.w;
        const int lidx = tile * 8192 + row * 64 + ((kg ^ (row & 7)) * 8);
        *(bf16x8*)(&sbuf[lidx]) = h;
      }
      __syncthreads();

      // ---- compute: 2 MFMA k-steps of 32 over this chunk ----
#pragma unroll
      for (int s = 0; s < 2; ++s) {
        const int sl = s * 4 + quad;  // 16B slot within row
        {  // S = cb x z
          bf16x8 a[4], b[4];
#pragma unroll
          for (int kf = 0; kf < 4; ++kf) {
            const int row = wavek * 64 + kf * 16 + r16;
            a[kf] = *(const bf16x8*)(&sbuf[2 * 8192 + row * 64 + ((sl ^ (row & 7)) * 8)]);
          }
#pragma unroll
          for (int nf = 0; nf < 4; ++nf) {
            const int row = waven * 64 + nf * 16 + r16;
            b[nf] = *(const bf16x8*)(&sbuf[0 * 8192 + row * 64 + ((sl ^ (row & 7)) * 8)]);
          }
#pragma unroll
          for (int kf = 0; kf < 4; ++kf)
#pragma unroll
            for (int nf = 0; nf < 4; ++nf)
              accS[kf][nf] =
                  __builtin_amdgcn_mfma_f32_16x16x32_bf16(a[kf], b[nf], accS[kf][nf], 0, 0, 0);
        }
        {  // X = gw x ctx
          bf16x8 a[4], b[4];
#pragma unroll
          for (int kf = 0; kf < 4; ++kf) {
            const int row = wavek * 64 + kf * 16 + r16;
            a[kf] = *(const bf16x8*)(&sbuf[3 * 8192 + row * 64 + ((sl ^ (row & 7)) * 8)]);
          }
#pragma unroll
          for (int nf = 0; nf < 4; ++nf) {
            const int row = waven * 64 + nf * 16 + r16;
            b[nf] = *(const bf16x8*)(&sbuf[1 * 8192 + row * 64 + ((sl ^ (row & 7)) * 8)]);
          }
#pragma unroll
          for (int kf = 0; kf < 4; ++kf)
#pragma unroll
            for (int nf = 0; nf < 4; ++nf)
              accX[kf][nf] =
                  __builtin_amdgcn_mfma_f32_16x16x32_bf16(a[kf], b[nf], accX[kf][nf], 0, 0, 0);
        }
      }
      __syncthreads();
    }

    // ---- epilogue: bias + top-2 update (per-lane, lane owns column n) ----
#pragma unroll
    for (int nf = 0; nf < 4; ++nf) {
#pragma unroll
      for (int kf = 0; kf < 4; ++kf) {
        const int kb = k0 + wavek * 64 + kf * 16 + quad * 4;
        f32x4 cn = *(const f32x4*)(cnorm + kb);
        f32x4 g4 = *(const f32x4*)(gb + kb);
        f32x4 a4 = *(const f32x4*)(arow[nf] + kb);
#pragma unroll
        for (int r = 0; r < 4; ++r) {
          float s = accS[kf][nf][r];
          float x = accX[kf][nf][r] + g4[r];
          float sig = __fdividef(1.f, 1.f + __expf(-a4[r]));
          float e2 = __expf(2.f * x);
          float th = 1.f - __fdividef(2.f, e2 + 1.f);
          float sc = cn[r] - 2.f * s - 0.8f * sig * (1.f + 0.5f * th);
          int kk = kb + r;
          if (sc < v1[nf]) {
            if (sc < v0[nf]) {
              v1[nf] = v0[nf]; i1[nf] = i0[nf];
              v0[nf] = sc;     i0[nf] = kk;
            } else {
              v1[nf] = sc; i1[nf] = kk;
            }
          }
        }
      }
    }
  }

  // ---- write per-lane top-2 candidate pairs ----
#pragma unroll
  for (int nf = 0; nf < 4; ++nf) {
    const int n = nout[nf];
    const int slot = ((bk * 2 + wavek) * 4 + quad) * 2;
    int2* p = cand + (size_t)n * 64 + slot;
    p[0] = make_int2(__float_as_int(v0[nf]), i0[nf]);
    p[1] = make_int2(__float_as_int(v1[nf]), i1[nf]);
  }
}

// ---------------------------------------------------------------------------
// Phase 2: exact f32 rescore of candidates within tau of approx min. One wave/row.
__global__ __launch_bounds__(256) void k_rescore(
    const float* __restrict__ zr, const float* __restrict__ zi,
    const float* __restrict__ cr, const float* __restrict__ ci,
    const int* __restrict__ prev, const float* __restrict__ cb,
    const float* __restrict__ adj, const float* __restrict__ gw,
    const float* __restrict__ gb, const int2* __restrict__ cand,
    int* __restrict__ widx, float* __restrict__ out_idx) {
  const int n = blockIdx.x * 4 + (threadIdx.x >> 6);
  const int lane = threadIdx.x & 63;

  f32x4 zv[4], xv[4];
#pragma unroll
  for (int j = 0; j < 4; ++j) {
    const int col = j * 256 + lane * 4;
    zv[j] = (col < DH) ? *(const f32x4*)(zr + (size_t)n * DH + col)
                       : *(const f32x4*)(zi + (size_t)n * DH + col - DH);
    xv[j] = (col < DH) ? *(const f32x4*)(cr + (size_t)n * DH + col)
                       : *(const f32x4*)(ci + (size_t)n * DH + col - DH);
  }

  int2 e = cand[(size_t)n * 64 + lane];
  float asc = __int_as_float(e.x);
  int aid = e.y;
  float m = asc;
#pragma unroll
  for (int off = 32; off; off >>= 1) m = fminf(m, __shfl_xor(m, off));
  unsigned long long mask = __ballot(asc <= m + 1.5f);

  const float* arow = adj + (size_t)prev[n] * KS;
  float best = 3.4e38f;
  int bid = 1 << 30;
  while (mask) {
    const int b = __ffsll((unsigned long long)mask) - 1;
    mask &= mask - 1;
    const int cidx = __shfl(aid, b);
    const float* crow = cb + (size_t)cidx * D2;
    const float* grow = gw + (size_t)cidx * D2;
    float sd = 0.f, xd = 0.f, cn = 0.f;
#pragma unroll
    for (int j = 0; j < 4; ++j) {
      f32x4 c4 = *(const f32x4*)(crow + j * 256 + lane * 4);
      f32x4 g4 = *(const f32x4*)(grow + j * 256 + lane * 4);
      sd += zv[j].x * c4.x + zv[j].y * c4.y + zv[j].z * c4.z + zv[j].w * c4.w;
      cn += c4.x * c4.x + c4.y * c4.y + c4.z * c4.z + c4.w * c4.w;
      xd += xv[j].x * g4.x + xv[j].y * g4.y + xv[j].z * g4.z + xv[j].w * g4.w;
    }
#pragma unroll
    for (int off = 32; off; off >>= 1) {
      sd += __shfl_xor(sd, off);
      cn += __shfl_xor(cn, off);
      xd += __shfl_xor(xd, off);
    }
    float xb = xd + gb[cidx];
    float sig = 1.f / (1.f + expf(-arow[cidx]));
    float th = tanhf(xb);
    float sc = cn - 2.f * sd - 0.8f * sig * (1.f + 0.5f * th);
    if (sc < best || (sc == best && cidx < bid)) { best = sc; bid = cidx; }
  }
  if (lane == 0) { widx[n] = bid; out_idx[n] = (float)bid; }
}

// ---------------------------------------------------------------------------
// Gather z_q, write straight-through output, loss partials, segment sums.
__global__ __launch_bounds__(256) void k_gather(
    const float* __restrict__ zr, const float* __restrict__ zi,
    const float* __restrict__ cb, const int* __restrict__ widx,
    float* __restrict__ out0, float* __restrict__ esum, float* __restrict__ cnt,
    double* __restrict__ loss) {
  __shared__ float red[4];
  const int n = blockIdx.x, tid = threadIdx.x;
  const int w = widx[n];
  const int e = tid * 4;
  f32x4 zv = (e < DH) ? *(const f32x4*)(zr + (size_t)n * DH + e)
                      : *(const f32x4*)(zi + (size_t)n * DH + e - DH);
  f32x4 cq = *(const f32x4*)(cb + (size_t)w * D2 + e);
  f32x4 d, o;
  d.x = cq.x - zv.x; d.y = cq.y - zv.y; d.z = cq.z - zv.z; d.w = cq.w - zv.w;
  o.x = zv.x + d.x;  o.y = zv.y + d.y;  o.z = zv.z + d.z;  o.w = zv.w + d.w;
  *(f32x4*)(out0 + (size_t)n * D2 + e) = o;
  atomicAdd(esum + (size_t)w * D2 + e + 0, zv.x);
  atomicAdd(esum + (size_t)w * D2 + e + 1, zv.y);
  atomicAdd(esum + (size_t)w * D2 + e + 2, zv.z);
  atomicAdd(esum + (size_t)w * D2 + e + 3, zv.w);
  float lp = d.x * d.x + d.y * d.y + d.z * d.z + d.w * d.w;
#pragma unroll
  for (int off = 32; off; off >>= 1) lp += __shfl_xor(lp, off);
  if ((tid & 63) == 0) red[tid >> 6] = lp;
  __syncthreads();
  if (tid == 0) {
    atomicAdd(loss, (double)(red[0] + red[1] + red[2] + red[3]));
    atomicAdd(cnt + w, 1.0f);
  }
}

// ---------------------------------------------------------------------------
// new_cluster_size (in place over counts in o4) + n_total + loss finalize.
__global__ __launch_bounds__(256) void k_cs(const float* __restrict__ cs_in,
                                            float* __restrict__ o4,
                                            float* __restrict__ ntot,
                                            const double* __restrict__ loss,
                                            float* __restrict__ o1) {
  __shared__ float red[4];
  const int k = blockIdx.x * 256 + threadIdx.x;
  const float c = o4[k];
  const float ncs = cs_in[k] * 0.99f + 0.01f * c;
  o4[k] = ncs;
  float lp = ncs;
#pragma unroll
  for (int off = 32; off; off >>= 1) lp += __shfl_xor(lp, off);
  if ((threadIdx.x & 63) == 0) red[threadIdx.x >> 6] = lp;
  __syncthreads();
  if (threadIdx.x == 0) atomicAdd(ntot, red[0] + red[1] + red[2] + red[3]);
  if (blockIdx.x == 0 && threadIdx.x == 0)
    o1[0] = (float)(1.25 * loss[0] / 16777216.0);
}

// ---------------------------------------------------------------------------
// new_embed_avg (in place over embed_sum in o5) and new_codebook.
__global__ __launch_bounds__(256) void k_final(const float* __restrict__ eavg,
                                               const float* __restrict__ o4,
                                               const float* __restrict__ ntotp,
                                               float* __restrict__ o3,
                                               float* __restrict__ o5) {
  const int k = blockIdx.x, tid = threadIdx.x;
  const float ntot = *ntotp;
  const float ncs = o4[k];
  const float csd = (ncs + 1e-6f) / (ntot + 0.008192f) * ntot;
#pragma unroll
  for (int j = 0; j < 4; ++j) {
    const int e = tid + j * 256;                  // coalesced dword streams
    const size_t idx = (size_t)k * D2 + e;
    const float es = o5[idx];
    const float nea = eavg[idx] * 0.99f + 0.01f * es;
    o5[idx] = nea;
    o3[idx] = nea / csd;
  }
}

// ---------------------------------------------------------------------------
extern "C" void kernel_launch(void* const* d_in, const int* in_sizes, int n_in,
                              void* d_out, int out_size, void* d_ws, size_t ws_size,
                              hipStream_t stream) {
  const float* zr = (const float*)d_in[0];
  const float* zi = (const float*)d_in[1];
  const float* cr = (const float*)d_in[2];
  const float* ci = (const float*)d_in[3];
  const int* pv = (const int*)d_in[4];
  const float* cb = (const float*)d_in[5];
  const float* adj = (const float*)d_in[6];
  const float* gw = (const float*)d_in[7];
  const float* gb = (const float*)d_in[8];
  const float* cs = (const float*)d_in[9];
  const float* ea = (const float*)d_in[10];

  float* out = (float*)d_out;
  float* o0 = out;                       // z_q_st        [N][1024]
  float* o1 = out + (size_t)NR * D2;     // loss          [1]
  float* o2 = o1 + 1;                    // min_indices   [N] (as float)
  float* o3 = o2 + NR;                   // new_codebook  [K][1024]
  float* o4 = o3 + (size_t)KS * D2;      // new_cluster   [K]
  float* o5 = o4 + KS;                   // new_embed_avg [K][1024]

  char* ws = (char*)d_ws;
  float* cnorm = (float*)(ws + WS_CNORM);
  double* loss = (double*)(ws + WS_LOSS);
  float* ntot = (float*)(ws + WS_NTOT);
  int2* cand = (int2*)(ws + WS_CAND);
  int* widx = (int*)(ws + WS_WIDX);

  hipMemsetAsync(o4, 0, KS * sizeof(float), stream);
  hipMemsetAsync(o5, 0, (size_t)KS * D2 * sizeof(float), stream);
  hipMemsetAsync(ws + WS_LOSS, 0, 32, stream);  // loss + ntot

  k_cnorm<<<KS, 64, 0, stream>>>(cb, cnorm);
  dim3 g1(NR / BN, KSPLIT);
  k_phase1<<<g1, 256, 0, stream>>>(zr, zi, cr, ci, pv, cb, adj, gw, gb, cnorm, cand);
  k_rescore<<<NR / 4, 256, 0, stream>>>(zr, zi, cr, ci, pv, cb, adj, gw, gb, cand, widx, o2);
  k_gather<<<NR, 256, 0, stream>>>(zr, zi, cb, widx, o0, o5, o4, loss);
  k_cs<<<KS / 256, 256, 0, stream>>>(cs, o4, ntot, loss, o1);
  k_final<<<KS, 256, 0, stream>>>(ea, o4, ntot, o3, o5);
}

// Round 3
// 1661.956 us; speedup vs baseline: 1.7316x; 1.7316x over previous
//
#include <hip/hip_runtime.h>
#include <hip/hip_bf16.h>

// GraphMemoryVQ: fused distance+graph-bias argmin (two-phase bf16-MFMA + f32 rescore),
// straight-through output, EMA codebook update.
// Sizes (fixed): N=16384, LATENT=512 (2D=1024), K=8192.
//
// R1 (resubmit R2 — prior round never acquired a GPU): phase1 rebuilt in the
// m97 structure — inputs pre-converted to bf16 ONCE (k_cvt) into pre-XOR-
// swizzled 16KB tiles, staged via global_load_lds(16B) into linear LDS, XOR
// applied on ds_read_b128 (rule #21). bf16 scratch lives in d_out (o0 holds
// zb/xb, o3 holds cbb/gwb) and is overwritten later.

#define NR 16384
#define DH 512
#define D2 1024
#define KS 8192
#define BK 128                 // k rows per block tile
#define BN 128                 // n rows per block tile
#define KC 64                  // inner-dim chunk staged in LDS
#define KSPLIT 4
#define KRANGE (KS / KSPLIT)   // 2048
#define NKT (KRANGE / BK)      // 16 k-tiles per block
#define TILE_B 16384           // bytes per [128][64] bf16 tile

typedef __bf16 bf16x8 __attribute__((ext_vector_type(8)));
typedef float f32x4 __attribute__((ext_vector_type(4)));

// ---- workspace layout (bytes) ----
#define WS_CNORM 0                       // 8192 f32
#define WS_LOSS  32768                   // f64 loss accumulator
#define WS_NTOT  32776                   // f32 n_total accumulator
#define WS_CAND  33024                   // int2 [NR][64] = 8 MB
#define WS_WIDX  (33024 + NR * 64 * 8)   // int [NR]

typedef const __attribute__((address_space(1))) void* gas_t;
typedef __attribute__((address_space(3))) void* las_t;
__device__ __forceinline__ void gld16(const void* g, void* l) {
  __builtin_amdgcn_global_load_lds((gas_t)g, (las_t)l, 16, 0, 0);
}

// swizzled LDS fragment read: tile t, row (0..127), 16B slot sl (0..7)
#define LDSF(t, row, sl)                                                     \
  (*(const bf16x8*)((const char*)sbuf + (t)*TILE_B + (row)*128 +             \
                    (((sl) ^ ((row) & 7)) * 16)))

// ---------------------------------------------------------------------------
// Pre-convert f32 inputs -> bf16, stored pre-swizzled in 16KB [128][64] tiles:
//   elem (r, c=chunk*64+sl*8+e) -> ((rb*16+chunk)*128 + rr)*64 + (sl^(rr&7))*8 + e
__global__ __launch_bounds__(256) void k_cvt(
    const float* __restrict__ zr, const float* __restrict__ zi,
    const float* __restrict__ cr, const float* __restrict__ ci,
    const float* __restrict__ cb, const float* __restrict__ gw,
    __hip_bfloat16* __restrict__ zb, __hip_bfloat16* __restrict__ xb,
    __hip_bfloat16* __restrict__ cbb, __hip_bfloat16* __restrict__ gwb) {
  const int flat = blockIdx.x * 256 + threadIdx.x;
  const int r_all = flat >> 7;   // logical row over all 4 arrays
  const int g = flat & 127;      // 8-elem group within row
  const float* s0;
  const float* s1;
  __hip_bfloat16* dst;
  int r;
  if (r_all < NR)                { r = r_all;              s0 = zr; s1 = zi;      dst = zb;  }
  else if (r_all < 2 * NR)       { r = r_all - NR;         s0 = cr; s1 = ci;      dst = xb;  }
  else if (r_all < 2 * NR + KS)  { r = r_all - 2 * NR;     s0 = cb; s1 = nullptr; dst = cbb; }
  else                           { r = r_all - 2 * NR - KS; s0 = gw; s1 = nullptr; dst = gwb; }
  const int c = g * 8;
  const float* src;
  if (s1) src = (c < DH) ? s0 + (size_t)r * DH + c : s1 + (size_t)r * DH + (c - DH);
  else    src = s0 + (size_t)r * D2 + c;
  f32x4 f0 = *(const f32x4*)src;
  f32x4 f1 = *(const f32x4*)(src + 4);
  bf16x8 h;
  h[0] = (__bf16)f0.x; h[1] = (__bf16)f0.y; h[2] = (__bf16)f0.z; h[3] = (__bf16)f0.w;
  h[4] = (__bf16)f1.x; h[5] = (__bf16)f1.y; h[6] = (__bf16)f1.z; h[7] = (__bf16)f1.w;
  const int chunk = g >> 3, sl = g & 7;
  const int rr = r & 127, rb = r >> 7;
  const int slS = sl ^ (rr & 7);
  const size_t off = ((size_t)(rb * 16 + chunk) * 128 + rr) * 64 + slS * 8;
  *(bf16x8*)(dst + off) = h;
}

// ---------------------------------------------------------------------------
// ||codebook_k||^2 in f32 (approx-phase bias; rescore recomputes exactly)
__global__ __launch_bounds__(64) void k_cnorm(const float* __restrict__ cb,
                                              float* __restrict__ cnorm) {
  int k = blockIdx.x, lane = threadIdx.x;
  const float* row = cb + (size_t)k * D2;
  float acc = 0.f;
#pragma unroll
  for (int j = 0; j < 4; ++j) {
    f32x4 v = *(const f32x4*)(row + j * 256 + lane * 4);
    acc += v.x * v.x + v.y * v.y + v.z * v.z + v.w * v.w;
  }
#pragma unroll
  for (int off = 32; off; off >>= 1) acc += __shfl_xor(acc, off);
  if (lane == 0) cnorm[k] = acc;
}

// ---------------------------------------------------------------------------
// Phase 1: approximate scores via bf16 MFMA, per-lane top-2 candidates.
// MFMA M axis = codebook k, N axis = data row n.
//   D: col(n) = lane&15, row(k) = (lane>>4)*4 + reg    [m89-verified]
__global__ __launch_bounds__(256, 2) void k_phase1(
    const int* __restrict__ prev,
    const __hip_bfloat16* __restrict__ zb, const __hip_bfloat16* __restrict__ xb,
    const __hip_bfloat16* __restrict__ cbb, const __hip_bfloat16* __restrict__ gwb,
    const float* __restrict__ adj, const float* __restrict__ gb,
    const float* __restrict__ cnorm, int2* __restrict__ cand) {
  // tiles: 0=z, 1=ctx, 2=cb, 3=gw ; each [128 rows][64 bf16], XOR-swizzled slots
  __shared__ unsigned short sbuf[4 * BK * KC];  // 64 KB

  const int tid = threadIdx.x;
  const int lane = tid & 63;
  const int wid = tid >> 6;      // 4 waves
  const int wavek = wid >> 1;    // k half (64 rows)
  const int waven = wid & 1;     // n half (64 cols)
  const int r16 = lane & 15;
  const int quad = lane >> 4;
  const int nb = blockIdx.x;
  const int n0 = nb * BN;
  const int bk = blockIdx.y;

  int nout[4];
  const float* arow[4];
#pragma unroll
  for (int nf = 0; nf < 4; ++nf) {
    nout[nf] = n0 + waven * 64 + nf * 16 + r16;
    arow[nf] = adj + (size_t)prev[nout[nf]] * KS;
  }

  float v0[4], v1[4];
  int i0[4], i1[4];
#pragma unroll
  for (int nf = 0; nf < 4; ++nf) { v0[nf] = 3.4e38f; v1[nf] = 3.4e38f; i0[nf] = 0; i1[nf] = 0; }

  for (int kt = 0; kt < NKT; ++kt) {
    const int ktg = bk * NKT + kt;     // global k-tile index (0..63)
    const int k0 = ktg * BK;
    f32x4 accS[4][4], accX[4][4];
#pragma unroll
    for (int a = 0; a < 4; ++a)
#pragma unroll
      for (int b = 0; b < 4; ++b) {
        accS[a][b] = (f32x4){0.f, 0.f, 0.f, 0.f};
        accX[a][b] = (f32x4){0.f, 0.f, 0.f, 0.f};
      }

    for (int c = 0; c < D2 / KC; ++c) {  // 16 chunks over the 1024 inner dim
      // ---- stage: bf16 tiles, direct global->LDS (linear dest, pre-swz src) ----
      const char* tb0 = (const char*)zb  + ((size_t)nb * 16 + c) * TILE_B;
      const char* tb1 = (const char*)xb  + ((size_t)nb * 16 + c) * TILE_B;
      const char* tb2 = (const char*)cbb + ((size_t)ktg * 16 + c) * TILE_B;
      const char* tb3 = (const char*)gwb + ((size_t)ktg * 16 + c) * TILE_B;
#pragma unroll
      for (int i = 0; i < 4; ++i) {
        const int o = (wid * 4 + i) * 1024;        // wave-uniform 1KB segment
        const int so = o + lane * 16;              // per-lane global source
        gld16(tb0 + so, (char*)sbuf + 0 * TILE_B + o);
        gld16(tb1 + so, (char*)sbuf + 1 * TILE_B + o);
        gld16(tb2 + so, (char*)sbuf + 2 * TILE_B + o);
        gld16(tb3 + so, (char*)sbuf + 3 * TILE_B + o);
      }
      __syncthreads();

      // ---- compute: 2 MFMA k-steps of 32 over this chunk ----
#pragma unroll
      for (int s = 0; s < 2; ++s) {
        const int sl = s * 4 + quad;  // 16B slot within row
        {  // S = cb x z
          bf16x8 a[4], b[4];
#pragma unroll
          for (int kf = 0; kf < 4; ++kf) a[kf] = LDSF(2, wavek * 64 + kf * 16 + r16, sl);
#pragma unroll
          for (int nf = 0; nf < 4; ++nf) b[nf] = LDSF(0, waven * 64 + nf * 16 + r16, sl);
#pragma unroll
          for (int kf = 0; kf < 4; ++kf)
#pragma unroll
            for (int nf = 0; nf < 4; ++nf)
              accS[kf][nf] =
                  __builtin_amdgcn_mfma_f32_16x16x32_bf16(a[kf], b[nf], accS[kf][nf], 0, 0, 0);
        }
        {  // X = gw x ctx
          bf16x8 a[4], b[4];
#pragma unroll
          for (int kf = 0; kf < 4; ++kf) a[kf] = LDSF(3, wavek * 64 + kf * 16 + r16, sl);
#pragma unroll
          for (int nf = 0; nf < 4; ++nf) b[nf] = LDSF(1, waven * 64 + nf * 16 + r16, sl);
#pragma unroll
          for (int kf = 0; kf < 4; ++kf)
#pragma unroll
            for (int nf = 0; nf < 4; ++nf)
              accX[kf][nf] =
                  __builtin_amdgcn_mfma_f32_16x16x32_bf16(a[kf], b[nf], accX[kf][nf], 0, 0, 0);
        }
      }
      __syncthreads();
    }

    // ---- epilogue: bias + top-2 update (lane owns column n) ----
#pragma unroll
    for (int kf = 0; kf < 4; ++kf) {
      const int kb = k0 + wavek * 64 + kf * 16 + quad * 4;
      const f32x4 cn = *(const f32x4*)(cnorm + kb);
      const f32x4 g4 = *(const f32x4*)(gb + kb);
#pragma unroll
      for (int nf = 0; nf < 4; ++nf) {
        const f32x4 a4 = *(const f32x4*)(arow[nf] + kb);
#pragma unroll
        for (int r = 0; r < 4; ++r) {
          float s = accS[kf][nf][r];
          float x = accX[kf][nf][r] + g4[r];
          float sig = __fdividef(1.f, 1.f + __expf(-a4[r]));
          float e2 = __expf(2.f * x);
          float th = 1.f - __fdividef(2.f, e2 + 1.f);
          float sc = cn[r] - 2.f * s - 0.8f * sig * (1.f + 0.5f * th);
          int kk = kb + r;
          if (sc < v1[nf]) {
            if (sc < v0[nf]) {
              v1[nf] = v0[nf]; i1[nf] = i0[nf];
              v0[nf] = sc;     i0[nf] = kk;
            } else {
              v1[nf] = sc; i1[nf] = kk;
            }
          }
        }
      }
    }
  }

  // ---- write per-lane top-2 candidate pairs ----
#pragma unroll
  for (int nf = 0; nf < 4; ++nf) {
    const int n = nout[nf];
    const int slot = ((bk * 2 + wavek) * 4 + quad) * 2;
    int2* p = cand + (size_t)n * 64 + slot;
    p[0] = make_int2(__float_as_int(v0[nf]), i0[nf]);
    p[1] = make_int2(__float_as_int(v1[nf]), i1[nf]);
  }
}

// ---------------------------------------------------------------------------
// Phase 2: exact f32 rescore of candidates within tau of approx min. One wave/row.
__global__ __launch_bounds__(256) void k_rescore(
    const float* __restrict__ zr, const float* __restrict__ zi,
    const float* __restrict__ cr, const float* __restrict__ ci,
    const int* __restrict__ prev, const float* __restrict__ cb,
    const float* __restrict__ adj, const float* __restrict__ gw,
    const float* __restrict__ gb, const int2* __restrict__ cand,
    int* __restrict__ widx, float* __restrict__ out_idx) {
  const int n = blockIdx.x * 4 + (threadIdx.x >> 6);
  const int lane = threadIdx.x & 63;

  f32x4 zv[4], xv[4];
#pragma unroll
  for (int j = 0; j < 4; ++j) {
    const int col = j * 256 + lane * 4;
    zv[j] = (col < DH) ? *(const f32x4*)(zr + (size_t)n * DH + col)
                       : *(const f32x4*)(zi + (size_t)n * DH + col - DH);
    xv[j] = (col < DH) ? *(const f32x4*)(cr + (size_t)n * DH + col)
                       : *(const f32x4*)(ci + (size_t)n * DH + col - DH);
  }

  int2 e = cand[(size_t)n * 64 + lane];
  float asc = __int_as_float(e.x);
  int aid = e.y;
  float m = asc;
#pragma unroll
  for (int off = 32; off; off >>= 1) m = fminf(m, __shfl_xor(m, off));
  unsigned long long mask = __ballot(asc <= m + 1.5f);

  const float* arow = adj + (size_t)prev[n] * KS;
  float best = 3.4e38f;
  int bid = 1 << 30;
  while (mask) {
    const int b = __ffsll((unsigned long long)mask) - 1;
    mask &= mask - 1;
    const int cidx = __shfl(aid, b);
    const float* crow = cb + (size_t)cidx * D2;
    const float* grow = gw + (size_t)cidx * D2;
    float sd = 0.f, xd = 0.f, cn = 0.f;
#pragma unroll
    for (int j = 0; j < 4; ++j) {
      f32x4 c4 = *(const f32x4*)(crow + j * 256 + lane * 4);
      f32x4 g4 = *(const f32x4*)(grow + j * 256 + lane * 4);
      sd += zv[j].x * c4.x + zv[j].y * c4.y + zv[j].z * c4.z + zv[j].w * c4.w;
      cn += c4.x * c4.x + c4.y * c4.y + c4.z * c4.z + c4.w * c4.w;
      xd += xv[j].x * g4.x + xv[j].y * g4.y + xv[j].z * g4.z + xv[j].w * g4.w;
    }
#pragma unroll
    for (int off = 32; off; off >>= 1) {
      sd += __shfl_xor(sd, off);
      cn += __shfl_xor(cn, off);
      xd += __shfl_xor(xd, off);
    }
    float xb2 = xd + gb[cidx];
    float sig = 1.f / (1.f + expf(-arow[cidx]));
    float th = tanhf(xb2);
    float sc = cn - 2.f * sd - 0.8f * sig * (1.f + 0.5f * th);
    if (sc < best || (sc == best && cidx < bid)) { best = sc; bid = cidx; }
  }
  if (lane == 0) { widx[n] = bid; out_idx[n] = (float)bid; }
}

// ---------------------------------------------------------------------------
// Gather z_q, write straight-through output, loss partials, segment sums.
__global__ __launch_bounds__(256) void k_gather(
    const float* __restrict__ zr, const float* __restrict__ zi,
    const float* __restrict__ cb, const int* __restrict__ widx,
    float* __restrict__ out0, float* __restrict__ esum, float* __restrict__ cnt,
    double* __restrict__ loss) {
  __shared__ float red[4];
  const int n = blockIdx.x, tid = threadIdx.x;
  const int w = widx[n];
  const int e = tid * 4;
  f32x4 zv = (e < DH) ? *(const f32x4*)(zr + (size_t)n * DH + e)
                      : *(const f32x4*)(zi + (size_t)n * DH + e - DH);
  f32x4 cq = *(const f32x4*)(cb + (size_t)w * D2 + e);
  f32x4 d, o;
  d.x = cq.x - zv.x; d.y = cq.y - zv.y; d.z = cq.z - zv.z; d.w = cq.w - zv.w;
  o.x = zv.x + d.x;  o.y = zv.y + d.y;  o.z = zv.z + d.z;  o.w = zv.w + d.w;
  *(f32x4*)(out0 + (size_t)n * D2 + e) = o;
  atomicAdd(esum + (size_t)w * D2 + e + 0, zv.x);
  atomicAdd(esum + (size_t)w * D2 + e + 1, zv.y);
  atomicAdd(esum + (size_t)w * D2 + e + 2, zv.z);
  atomicAdd(esum + (size_t)w * D2 + e + 3, zv.w);
  float lp = d.x * d.x + d.y * d.y + d.z * d.z + d.w * d.w;
#pragma unroll
  for (int off = 32; off; off >>= 1) lp += __shfl_xor(lp, off);
  if ((tid & 63) == 0) red[tid >> 6] = lp;
  __syncthreads();
  if (tid == 0) {
    atomicAdd(loss, (double)(red[0] + red[1] + red[2] + red[3]));
    atomicAdd(cnt + w, 1.0f);
  }
}

// ---------------------------------------------------------------------------
// new_cluster_size (in place over counts in o4) + n_total + loss finalize.
__global__ __launch_bounds__(256) void k_cs(const float* __restrict__ cs_in,
                                            float* __restrict__ o4,
                                            float* __restrict__ ntot,
                                            const double* __restrict__ loss,
                                            float* __restrict__ o1) {
  __shared__ float red[4];
  const int k = blockIdx.x * 256 + threadIdx.x;
  const float c = o4[k];
  const float ncs = cs_in[k] * 0.99f + 0.01f * c;
  o4[k] = ncs;
  float lp = ncs;
#pragma unroll
  for (int off = 32; off; off >>= 1) lp += __shfl_xor(lp, off);
  if ((threadIdx.x & 63) == 0) red[threadIdx.x >> 6] = lp;
  __syncthreads();
  if (threadIdx.x == 0) atomicAdd(ntot, red[0] + red[1] + red[2] + red[3]);
  if (blockIdx.x == 0 && threadIdx.x == 0)
    o1[0] = (float)(1.25 * loss[0] / 16777216.0);
}

// ---------------------------------------------------------------------------
// new_embed_avg (in place over embed_sum in o5) and new_codebook.
__global__ __launch_bounds__(256) void k_final(const float* __restrict__ eavg,
                                               const float* __restrict__ o4,
                                               const float* __restrict__ ntotp,
                                               float* __restrict__ o3,
                                               float* __restrict__ o5) {
  const int k = blockIdx.x, tid = threadIdx.x;
  const float ntot = *ntotp;
  const float ncs = o4[k];
  const float csd = (ncs + 1e-6f) / (ntot + 0.008192f) * ntot;
#pragma unroll
  for (int j = 0; j < 4; ++j) {
    const int e = tid + j * 256;
    const size_t idx = (size_t)k * D2 + e;
    const float es = o5[idx];
    const float nea = eavg[idx] * 0.99f + 0.01f * es;
    o5[idx] = nea;
    o3[idx] = nea / csd;
  }
}

// ---------------------------------------------------------------------------
extern "C" void kernel_launch(void* const* d_in, const int* in_sizes, int n_in,
                              void* d_out, int out_size, void* d_ws, size_t ws_size,
                              hipStream_t stream) {
  const float* zr = (const float*)d_in[0];
  const float* zi = (const float*)d_in[1];
  const float* cr = (const float*)d_in[2];
  const float* ci = (const float*)d_in[3];
  const int* pv = (const int*)d_in[4];
  const float* cb = (const float*)d_in[5];
  const float* adj = (const float*)d_in[6];
  const float* gw = (const float*)d_in[7];
  const float* gb = (const float*)d_in[8];
  const float* cs = (const float*)d_in[9];
  const float* ea = (const float*)d_in[10];

  float* out = (float*)d_out;
  float* o0 = out;                       // z_q_st        [N][1024]
  float* o1 = out + (size_t)NR * D2;     // loss          [1]
  float* o2 = o1 + 1;                    // min_indices   [N]
  float* o3 = o2 + NR;                   // new_codebook  [K][1024]
  float* o4 = o3 + (size_t)KS * D2;      // new_cluster   [K]
  float* o5 = o4 + KS;                   // new_embed_avg [K][1024]

  char* ws = (char*)d_ws;
  float* cnorm = (float*)(ws + WS_CNORM);
  double* loss = (double*)(ws + WS_LOSS);
  float* ntot = (float*)(ws + WS_NTOT);
  int2* cand = (int2*)(ws + WS_CAND);
  int* widx = (int*)(ws + WS_WIDX);

  // bf16 scratch inside d_out (overwritten by k_gather / k_final afterwards).
  // zb+xb = 64MB fits o0 exactly; cbb+gwb = 32MB in o3 (aligned up 16B, may
  // overrun <=12B into o4, which is memset AFTER phase1).
  __hip_bfloat16* zb = (__hip_bfloat16*)o0;
  __hip_bfloat16* xb = zb + (size_t)NR * D2;
  uintptr_t cba = ((uintptr_t)o3 + 15) & ~(uintptr_t)15;
  __hip_bfloat16* cbb = (__hip_bfloat16*)cba;
  __hip_bfloat16* gwb = cbb + (size_t)KS * D2;

  k_cvt<<<(2 * NR + 2 * KS) * 128 / 256, 256, 0, stream>>>(zr, zi, cr, ci, cb, gw,
                                                           zb, xb, cbb, gwb);
  k_cnorm<<<KS, 64, 0, stream>>>(cb, cnorm);
  dim3 g1(NR / BN, KSPLIT);
  k_phase1<<<g1, 256, 0, stream>>>(pv, zb, xb, cbb, gwb, adj, gb, cnorm, cand);

  hipMemsetAsync(o4, 0, KS * sizeof(float), stream);
  hipMemsetAsync(o5, 0, (size_t)KS * D2 * sizeof(float), stream);
  hipMemsetAsync(ws + WS_LOSS, 0, 32, stream);  // loss + ntot

  k_rescore<<<NR / 4, 256, 0, stream>>>(zr, zi, cr, ci, pv, cb, adj, gw, gb, cand, widx, o2);
  k_gather<<<NR, 256, 0, stream>>>(zr, zi, cb, widx, o0, o5, o4, loss);
  k_cs<<<KS / 256, 256, 0, stream>>>(cs, o4, ntot, loss, o1);
  k_final<<<KS, 256, 0, stream>>>(ea, o4, ntot, o3, o5);
}

// Round 4
// 1597.719 us; speedup vs baseline: 1.8012x; 1.0402x over previous
//
#include <hip/hip_runtime.h>
#include <hip/hip_bf16.h>

// GraphMemoryVQ: fused distance+graph-bias argmin (two-phase bf16-MFMA + f32 rescore),
// straight-through output, EMA codebook update.
// Sizes (fixed): N=16384, LATENT=512 (2D=1024), K=8192.
//
// R1: phase1 in m97 structure (bf16 pre-convert, pre-swizzled tiles,
//     global_load_lds 16B, XOR on ds_read_b128).   -> 806 us, MfmaUtil 30%
// R4: tail rebuilt — k_gather's 16.7M f32 atomics replaced by
//     count/scan/scatter/segsum (bucket sum, no atomics); straight-through
//     output + loss folded into k_rescore. Scratch overlays dead cand region.

#define NR 16384
#define DH 512
#define D2 1024
#define KS 8192
#define BK 128                 // k rows per block tile
#define BN 128                 // n rows per block tile
#define KC 64                  // inner-dim chunk staged in LDS
#define KSPLIT 4
#define KRANGE (KS / KSPLIT)   // 2048
#define NKT (KRANGE / BK)      // 16 k-tiles per block
#define TILE_B 16384           // bytes per [128][64] bf16 tile

typedef __bf16 bf16x8 __attribute__((ext_vector_type(8)));
typedef float f32x4 __attribute__((ext_vector_type(4)));

// ---- workspace layout (bytes) ----
#define WS_CNORM 0                       // 8192 f32
#define WS_LOSS  32768                   // f64 loss accumulator
#define WS_NTOT  32776                   // f32 n_total accumulator
#define WS_CAND  33024                   // int2 [NR][64] = 8 MB
#define WS_WIDX  (33024 + NR * 64 * 8)   // int [NR]
// overlays INSIDE the cand region (cand is dead after k_rescore):
#define OV_CNTI  WS_CAND                 // int [KS]   32 KB
#define OV_OFF   (WS_CAND + 32768)       // int [KS]   32 KB
#define OV_POS   (WS_CAND + 65536)       // int [NR]   64 KB
#define OV_BKT   (WS_CAND + 131072)      // int [NR]   64 KB

typedef const __attribute__((address_space(1))) void* gas_t;
typedef __attribute__((address_space(3))) void* las_t;
__device__ __forceinline__ void gld16(const void* g, void* l) {
  __builtin_amdgcn_global_load_lds((gas_t)g, (las_t)l, 16, 0, 0);
}

// swizzled LDS fragment read: tile t, row (0..127), 16B slot sl (0..7)
#define LDSF(t, row, sl)                                                     \
  (*(const bf16x8*)((const char*)sbuf + (t)*TILE_B + (row)*128 +             \
                    (((sl) ^ ((row) & 7)) * 16)))

// ---------------------------------------------------------------------------
// Pre-convert f32 inputs -> bf16, stored pre-swizzled in 16KB [128][64] tiles:
//   elem (r, c=chunk*64+sl*8+e) -> ((rb*16+chunk)*128 + rr)*64 + (sl^(rr&7))*8 + e
__global__ __launch_bounds__(256) void k_cvt(
    const float* __restrict__ zr, const float* __restrict__ zi,
    const float* __restrict__ cr, const float* __restrict__ ci,
    const float* __restrict__ cb, const float* __restrict__ gw,
    __hip_bfloat16* __restrict__ zb, __hip_bfloat16* __restrict__ xb,
    __hip_bfloat16* __restrict__ cbb, __hip_bfloat16* __restrict__ gwb) {
  const int flat = blockIdx.x * 256 + threadIdx.x;
  const int r_all = flat >> 7;   // logical row over all 4 arrays
  const int g = flat & 127;      // 8-elem group within row
  const float* s0;
  const float* s1;
  __hip_bfloat16* dst;
  int r;
  if (r_all < NR)                { r = r_all;              s0 = zr; s1 = zi;      dst = zb;  }
  else if (r_all < 2 * NR)       { r = r_all - NR;         s0 = cr; s1 = ci;      dst = xb;  }
  else if (r_all < 2 * NR + KS)  { r = r_all - 2 * NR;     s0 = cb; s1 = nullptr; dst = cbb; }
  else                           { r = r_all - 2 * NR - KS; s0 = gw; s1 = nullptr; dst = gwb; }
  const int c = g * 8;
  const float* src;
  if (s1) src = (c < DH) ? s0 + (size_t)r * DH + c : s1 + (size_t)r * DH + (c - DH);
  else    src = s0 + (size_t)r * D2 + c;
  f32x4 f0 = *(const f32x4*)src;
  f32x4 f1 = *(const f32x4*)(src + 4);
  bf16x8 h;
  h[0] = (__bf16)f0.x; h[1] = (__bf16)f0.y; h[2] = (__bf16)f0.z; h[3] = (__bf16)f0.w;
  h[4] = (__bf16)f1.x; h[5] = (__bf16)f1.y; h[6] = (__bf16)f1.z; h[7] = (__bf16)f1.w;
  const int chunk = g >> 3, sl = g & 7;
  const int rr = r & 127, rb = r >> 7;
  const int slS = sl ^ (rr & 7);
  const size_t off = ((size_t)(rb * 16 + chunk) * 128 + rr) * 64 + slS * 8;
  *(bf16x8*)(dst + off) = h;
}

// ---------------------------------------------------------------------------
// ||codebook_k||^2 in f32 (approx-phase bias; rescore recomputes exactly)
__global__ __launch_bounds__(64) void k_cnorm(const float* __restrict__ cb,
                                              float* __restrict__ cnorm) {
  int k = blockIdx.x, lane = threadIdx.x;
  const float* row = cb + (size_t)k * D2;
  float acc = 0.f;
#pragma unroll
  for (int j = 0; j < 4; ++j) {
    f32x4 v = *(const f32x4*)(row + j * 256 + lane * 4);
    acc += v.x * v.x + v.y * v.y + v.z * v.z + v.w * v.w;
  }
#pragma unroll
  for (int off = 32; off; off >>= 1) acc += __shfl_xor(acc, off);
  if (lane == 0) cnorm[k] = acc;
}

// ---------------------------------------------------------------------------
// Phase 1: approximate scores via bf16 MFMA, per-lane top-2 candidates.
// MFMA M axis = codebook k, N axis = data row n.
//   D: col(n) = lane&15, row(k) = (lane>>4)*4 + reg    [m89-verified]
__global__ __launch_bounds__(256, 2) void k_phase1(
    const int* __restrict__ prev,
    const __hip_bfloat16* __restrict__ zb, const __hip_bfloat16* __restrict__ xb,
    const __hip_bfloat16* __restrict__ cbb, const __hip_bfloat16* __restrict__ gwb,
    const float* __restrict__ adj, const float* __restrict__ gb,
    const float* __restrict__ cnorm, int2* __restrict__ cand) {
  // tiles: 0=z, 1=ctx, 2=cb, 3=gw ; each [128 rows][64 bf16], XOR-swizzled slots
  __shared__ unsigned short sbuf[4 * BK * KC];  // 64 KB

  const int tid = threadIdx.x;
  const int lane = tid & 63;
  const int wid = tid >> 6;      // 4 waves
  const int wavek = wid >> 1;    // k half (64 rows)
  const int waven = wid & 1;     // n half (64 cols)
  const int r16 = lane & 15;
  const int quad = lane >> 4;
  const int nb = blockIdx.x;
  const int n0 = nb * BN;
  const int bk = blockIdx.y;

  int nout[4];
  const float* arow[4];
#pragma unroll
  for (int nf = 0; nf < 4; ++nf) {
    nout[nf] = n0 + waven * 64 + nf * 16 + r16;
    arow[nf] = adj + (size_t)prev[nout[nf]] * KS;
  }

  float v0[4], v1[4];
  int i0[4], i1[4];
#pragma unroll
  for (int nf = 0; nf < 4; ++nf) { v0[nf] = 3.4e38f; v1[nf] = 3.4e38f; i0[nf] = 0; i1[nf] = 0; }

  for (int kt = 0; kt < NKT; ++kt) {
    const int ktg = bk * NKT + kt;     // global k-tile index (0..63)
    const int k0 = ktg * BK;
    f32x4 accS[4][4], accX[4][4];
#pragma unroll
    for (int a = 0; a < 4; ++a)
#pragma unroll
      for (int b = 0; b < 4; ++b) {
        accS[a][b] = (f32x4){0.f, 0.f, 0.f, 0.f};
        accX[a][b] = (f32x4){0.f, 0.f, 0.f, 0.f};
      }

    for (int c = 0; c < D2 / KC; ++c) {  // 16 chunks over the 1024 inner dim
      // ---- stage: bf16 tiles, direct global->LDS (linear dest, pre-swz src) ----
      const char* tb0 = (const char*)zb  + ((size_t)nb * 16 + c) * TILE_B;
      const char* tb1 = (const char*)xb  + ((size_t)nb * 16 + c) * TILE_B;
      const char* tb2 = (const char*)cbb + ((size_t)ktg * 16 + c) * TILE_B;
      const char* tb3 = (const char*)gwb + ((size_t)ktg * 16 + c) * TILE_B;
#pragma unroll
      for (int i = 0; i < 4; ++i) {
        const int o = (wid * 4 + i) * 1024;        // wave-uniform 1KB segment
        const int so = o + lane * 16;              // per-lane global source
        gld16(tb0 + so, (char*)sbuf + 0 * TILE_B + o);
        gld16(tb1 + so, (char*)sbuf + 1 * TILE_B + o);
        gld16(tb2 + so, (char*)sbuf + 2 * TILE_B + o);
        gld16(tb3 + so, (char*)sbuf + 3 * TILE_B + o);
      }
      __syncthreads();

      // ---- compute: 2 MFMA k-steps of 32 over this chunk ----
#pragma unroll
      for (int s = 0; s < 2; ++s) {
        const int sl = s * 4 + quad;  // 16B slot within row
        {  // S = cb x z
          bf16x8 a[4], b[4];
#pragma unroll
          for (int kf = 0; kf < 4; ++kf) a[kf] = LDSF(2, wavek * 64 + kf * 16 + r16, sl);
#pragma unroll
          for (int nf = 0; nf < 4; ++nf) b[nf] = LDSF(0, waven * 64 + nf * 16 + r16, sl);
#pragma unroll
          for (int kf = 0; kf < 4; ++kf)
#pragma unroll
            for (int nf = 0; nf < 4; ++nf)
              accS[kf][nf] =
                  __builtin_amdgcn_mfma_f32_16x16x32_bf16(a[kf], b[nf], accS[kf][nf], 0, 0, 0);
        }
        {  // X = gw x ctx
          bf16x8 a[4], b[4];
#pragma unroll
          for (int kf = 0; kf < 4; ++kf) a[kf] = LDSF(3, wavek * 64 + kf * 16 + r16, sl);
#pragma unroll
          for (int nf = 0; nf < 4; ++nf) b[nf] = LDSF(1, waven * 64 + nf * 16 + r16, sl);
#pragma unroll
          for (int kf = 0; kf < 4; ++kf)
#pragma unroll
            for (int nf = 0; nf < 4; ++nf)
              accX[kf][nf] =
                  __builtin_amdgcn_mfma_f32_16x16x32_bf16(a[kf], b[nf], accX[kf][nf], 0, 0, 0);
        }
      }
      __syncthreads();
    }

    // ---- epilogue: bias + top-2 update (lane owns column n) ----
#pragma unroll
    for (int kf = 0; kf < 4; ++kf) {
      const int kb = k0 + wavek * 64 + kf * 16 + quad * 4;
      const f32x4 cn = *(const f32x4*)(cnorm + kb);
      const f32x4 g4 = *(const f32x4*)(gb + kb);
#pragma unroll
      for (int nf = 0; nf < 4; ++nf) {
        const f32x4 a4 = *(const f32x4*)(arow[nf] + kb);
#pragma unroll
        for (int r = 0; r < 4; ++r) {
          float s = accS[kf][nf][r];
          float x = accX[kf][nf][r] + g4[r];
          float sig = __fdividef(1.f, 1.f + __expf(-a4[r]));
          float e2 = __expf(2.f * x);
          float th = 1.f - __fdividef(2.f, e2 + 1.f);
          float sc = cn[r] - 2.f * s - 0.8f * sig * (1.f + 0.5f * th);
          int kk = kb + r;
          if (sc < v1[nf]) {
            if (sc < v0[nf]) {
              v1[nf] = v0[nf]; i1[nf] = i0[nf];
              v0[nf] = sc;     i0[nf] = kk;
            } else {
              v1[nf] = sc; i1[nf] = kk;
            }
          }
        }
      }
    }
  }

  // ---- write per-lane top-2 candidate pairs ----
#pragma unroll
  for (int nf = 0; nf < 4; ++nf) {
    const int n = nout[nf];
    const int slot = ((bk * 2 + wavek) * 4 + quad) * 2;
    int2* p = cand + (size_t)n * 64 + slot;
    p[0] = make_int2(__float_as_int(v0[nf]), i0[nf]);
    p[1] = make_int2(__float_as_int(v1[nf]), i1[nf]);
  }
}

// ---------------------------------------------------------------------------
// Phase 2: exact f32 rescore of candidates within tau of approx min (one wave
// per row), then straight-through output + loss partial (fused, R4).
__global__ __launch_bounds__(256) void k_rescore(
    const float* __restrict__ zr, const float* __restrict__ zi,
    const float* __restrict__ cr, const float* __restrict__ ci,
    const int* __restrict__ prev, const float* __restrict__ cb,
    const float* __restrict__ adj, const float* __restrict__ gw,
    const float* __restrict__ gb, const int2* __restrict__ cand,
    int* __restrict__ widx, float* __restrict__ out_idx,
    float* __restrict__ out0, double* __restrict__ loss) {
  const int n = blockIdx.x * 4 + (threadIdx.x >> 6);
  const int lane = threadIdx.x & 63;

  f32x4 zv[4], xv[4];
#pragma unroll
  for (int j = 0; j < 4; ++j) {
    const int col = j * 256 + lane * 4;
    zv[j] = (col < DH) ? *(const f32x4*)(zr + (size_t)n * DH + col)
                       : *(const f32x4*)(zi + (size_t)n * DH + col - DH);
    xv[j] = (col < DH) ? *(const f32x4*)(cr + (size_t)n * DH + col)
                       : *(const f32x4*)(ci + (size_t)n * DH + col - DH);
  }

  int2 e = cand[(size_t)n * 64 + lane];
  float asc = __int_as_float(e.x);
  int aid = e.y;
  float m = asc;
#pragma unroll
  for (int off = 32; off; off >>= 1) m = fminf(m, __shfl_xor(m, off));
  unsigned long long mask = __ballot(asc <= m + 1.5f);

  const float* arow = adj + (size_t)prev[n] * KS;
  float best = 3.4e38f;
  int bid = 1 << 30;
  while (mask) {
    const int b = __ffsll((unsigned long long)mask) - 1;
    mask &= mask - 1;
    const int cidx = __shfl(aid, b);
    const float* crow = cb + (size_t)cidx * D2;
    const float* grow = gw + (size_t)cidx * D2;
    float sd = 0.f, xd = 0.f, cn = 0.f;
#pragma unroll
    for (int j = 0; j < 4; ++j) {
      f32x4 c4 = *(const f32x4*)(crow + j * 256 + lane * 4);
      f32x4 g4 = *(const f32x4*)(grow + j * 256 + lane * 4);
      sd += zv[j].x * c4.x + zv[j].y * c4.y + zv[j].z * c4.z + zv[j].w * c4.w;
      cn += c4.x * c4.x + c4.y * c4.y + c4.z * c4.z + c4.w * c4.w;
      xd += xv[j].x * g4.x + xv[j].y * g4.y + xv[j].z * g4.z + xv[j].w * g4.w;
    }
#pragma unroll
    for (int off = 32; off; off >>= 1) {
      sd += __shfl_xor(sd, off);
      cn += __shfl_xor(cn, off);
      xd += __shfl_xor(xd, off);
    }
    float xb2 = xd + gb[cidx];
    float sig = 1.f / (1.f + expf(-arow[cidx]));
    float th = tanhf(xb2);
    float sc = cn - 2.f * sd - 0.8f * sig * (1.f + 0.5f * th);
    if (sc < best || (sc == best && cidx < bid)) { best = sc; bid = cidx; }
  }
  // best/bid are uniform across the wave (all lanes saw identical reduced values)
  const float* crow = cb + (size_t)bid * D2;
  float lp = 0.f;
#pragma unroll
  for (int j = 0; j < 4; ++j) {
    const int col = j * 256 + lane * 4;
    f32x4 cq = *(const f32x4*)(crow + col);
    f32x4 d, o;
    d.x = cq.x - zv[j].x; d.y = cq.y - zv[j].y; d.z = cq.z - zv[j].z; d.w = cq.w - zv[j].w;
    o.x = zv[j].x + d.x;  o.y = zv[j].y + d.y;  o.z = zv[j].z + d.z;  o.w = zv[j].w + d.w;
    *(f32x4*)(out0 + (size_t)n * D2 + col) = o;
    lp += d.x * d.x + d.y * d.y + d.z * d.z + d.w * d.w;
  }
#pragma unroll
  for (int off = 32; off; off >>= 1) lp += __shfl_xor(lp, off);
  if (lane == 0) {
    widx[n] = bid;
    out_idx[n] = (float)bid;
    atomicAdd(loss, (double)lp);
  }
}

// ---------------------------------------------------------------------------
// Bucket build: one atomic per row (cnti pre-zeroed).
__global__ __launch_bounds__(256) void k_count(const int* __restrict__ widx,
                                               int* __restrict__ cnti,
                                               int* __restrict__ pos) {
  const int n = blockIdx.x * 256 + threadIdx.x;
  pos[n] = atomicAdd(&cnti[widx[n]], 1);
}

// Exclusive prefix sum over 8192 counts (single block).
__global__ __launch_bounds__(256) void k_scan(const int* __restrict__ cnti,
                                              int* __restrict__ off) {
  __shared__ int part[256];
  const int t = threadIdx.x;
  int v[32];
  int s = 0;
#pragma unroll
  for (int i = 0; i < 32; ++i) { v[i] = s; s += cnti[t * 32 + i]; }
  part[t] = s;
  __syncthreads();
  if (t == 0) {
    int run = 0;
    for (int i = 0; i < 256; ++i) { int tmp = part[i]; part[i] = run; run += tmp; }
  }
  __syncthreads();
  const int base = part[t];
#pragma unroll
  for (int i = 0; i < 32; ++i) off[t * 32 + i] = base + v[i];
}

__global__ __launch_bounds__(256) void k_scatter(const int* __restrict__ widx,
                                                 const int* __restrict__ pos,
                                                 const int* __restrict__ off,
                                                 int* __restrict__ bucket) {
  const int n = blockIdx.x * 256 + threadIdx.x;
  bucket[off[widx[n]] + pos[n]] = n;
}

// Per-codebook-entry segment sum of z rows (no atomics, writes full esum).
__global__ __launch_bounds__(256) void k_segsum(
    const float* __restrict__ zr, const float* __restrict__ zi,
    const int* __restrict__ cnti, const int* __restrict__ off,
    const int* __restrict__ bucket, float* __restrict__ esum) {
  const int k = blockIdx.x, tid = threadIdx.x;
  const int c = cnti[k], o = off[k];
  const int e = tid * 4;
  const float* src = (e < DH) ? zr + e : zi + (e - DH);
  f32x4 acc = (f32x4){0.f, 0.f, 0.f, 0.f};
  for (int i = 0; i < c; ++i) {
    const int n = bucket[o + i];
    f32x4 v = *(const f32x4*)(src + (size_t)n * DH);
    acc.x += v.x; acc.y += v.y; acc.z += v.z; acc.w += v.w;
  }
  *(f32x4*)(esum + (size_t)k * D2 + e) = acc;
}

// ---------------------------------------------------------------------------
// new_cluster_size from int counts + n_total + loss finalize.
__global__ __launch_bounds__(256) void k_cs(const float* __restrict__ cs_in,
                                            const int* __restrict__ cnti,
                                            float* __restrict__ o4,
                                            float* __restrict__ ntot,
                                            const double* __restrict__ loss,
                                            float* __restrict__ o1) {
  __shared__ float red[4];
  const int k = blockIdx.x * 256 + threadIdx.x;
  const float ncs = cs_in[k] * 0.99f + 0.01f * (float)cnti[k];
  o4[k] = ncs;
  float lp = ncs;
#pragma unroll
  for (int off = 32; off; off >>= 1) lp += __shfl_xor(lp, off);
  if ((threadIdx.x & 63) == 0) red[threadIdx.x >> 6] = lp;
  __syncthreads();
  if (threadIdx.x == 0) atomicAdd(ntot, red[0] + red[1] + red[2] + red[3]);
  if (blockIdx.x == 0 && threadIdx.x == 0)
    o1[0] = (float)(1.25 * loss[0] / 16777216.0);
}

// ---------------------------------------------------------------------------
// new_embed_avg (in place over embed_sum in o5) and new_codebook.
__global__ __launch_bounds__(256) void k_final(const float* __restrict__ eavg,
                                               const float* __restrict__ o4,
                                               const float* __restrict__ ntotp,
                                               float* __restrict__ o3,
                                               float* __restrict__ o5) {
  const int k = blockIdx.x, tid = threadIdx.x;
  const float ntot = *ntotp;
  const float ncs = o4[k];
  const float csd = (ncs + 1e-6f) / (ntot + 0.008192f) * ntot;
#pragma unroll
  for (int j = 0; j < 4; ++j) {
    const int e = tid + j * 256;
    const size_t idx = (size_t)k * D2 + e;
    const float es = o5[idx];
    const float nea = eavg[idx] * 0.99f + 0.01f * es;
    o5[idx] = nea;
    o3[idx] = nea / csd;
  }
}

// ---------------------------------------------------------------------------
extern "C" void kernel_launch(void* const* d_in, const int* in_sizes, int n_in,
                              void* d_out, int out_size, void* d_ws, size_t ws_size,
                              hipStream_t stream) {
  const float* zr = (const float*)d_in[0];
  const float* zi = (const float*)d_in[1];
  const float* cr = (const float*)d_in[2];
  const float* ci = (const float*)d_in[3];
  const int* pv = (const int*)d_in[4];
  const float* cb = (const float*)d_in[5];
  const float* adj = (const float*)d_in[6];
  const float* gw = (const float*)d_in[7];
  const float* gb = (const float*)d_in[8];
  const float* cs = (const float*)d_in[9];
  const float* ea = (const float*)d_in[10];

  float* out = (float*)d_out;
  float* o0 = out;                       // z_q_st        [N][1024]
  float* o1 = out + (size_t)NR * D2;     // loss          [1]
  float* o2 = o1 + 1;                    // min_indices   [N]
  float* o3 = o2 + NR;                   // new_codebook  [K][1024]
  float* o4 = o3 + (size_t)KS * D2;      // new_cluster   [K]
  float* o5 = o4 + KS;                   // new_embed_avg [K][1024]

  char* ws = (char*)d_ws;
  float* cnorm = (float*)(ws + WS_CNORM);
  double* loss = (double*)(ws + WS_LOSS);
  float* ntot = (float*)(ws + WS_NTOT);
  int2* cand = (int2*)(ws + WS_CAND);
  int* widx = (int*)(ws + WS_WIDX);
  int* cnti = (int*)(ws + OV_CNTI);      // overlays cand (dead after rescore)
  int* offp = (int*)(ws + OV_OFF);
  int* pos  = (int*)(ws + OV_POS);
  int* bkt  = (int*)(ws + OV_BKT);

  // bf16 scratch inside d_out (overwritten later: o0 by k_rescore, o3 by k_final).
  __hip_bfloat16* zb = (__hip_bfloat16*)o0;
  __hip_bfloat16* xb = zb + (size_t)NR * D2;
  uintptr_t cba = ((uintptr_t)o3 + 15) & ~(uintptr_t)15;
  __hip_bfloat16* cbb = (__hip_bfloat16*)cba;
  __hip_bfloat16* gwb = cbb + (size_t)KS * D2;

  k_cvt<<<(2 * NR + 2 * KS) * 128 / 256, 256, 0, stream>>>(zr, zi, cr, ci, cb, gw,
                                                           zb, xb, cbb, gwb);
  k_cnorm<<<KS, 64, 0, stream>>>(cb, cnorm);
  dim3 g1(NR / BN, KSPLIT);
  k_phase1<<<g1, 256, 0, stream>>>(pv, zb, xb, cbb, gwb, adj, gb, cnorm, cand);

  hipMemsetAsync(ws + WS_LOSS, 0, 32, stream);  // loss + ntot
  k_rescore<<<NR / 4, 256, 0, stream>>>(zr, zi, cr, ci, pv, cb, adj, gw, gb,
                                        cand, widx, o2, o0, loss);

  hipMemsetAsync(cnti, 0, KS * sizeof(int), stream);  // cand now dead
  k_count<<<NR / 256, 256, 0, stream>>>(widx, cnti, pos);
  k_scan<<<1, 256, 0, stream>>>(cnti, offp);
  k_scatter<<<NR / 256, 256, 0, stream>>>(widx, pos, offp, bkt);
  k_segsum<<<KS, 256, 0, stream>>>(zr, zi, cnti, offp, bkt, o5);
  k_cs<<<KS / 256, 256, 0, stream>>>(cs, cnti, o4, ntot, loss, o1);
  k_final<<<KS, 256, 0, stream>>>(ea, o4, ntot, o3, o5);
}